// Round 1
// baseline (148.371 us; speedup 1.0000x reference)
//
#include <hip/hip_runtime.h>
#include <float.h>
#include <math.h>

// DSNT double loss: B=32, C=8, H=256, W=256, fp32 in, scalar fp32 out.
// One block per (b,c) heatmap; 1024 threads; single pass over both arrays
// with online softmax (input) + argmax (target); block reduce; atomicAdd.

#define HW 65536          // H*W
#define BLOCK 1024        // threads per block (16 waves)
#define F4_PER_THREAD 16  // (HW/4)/BLOCK

__global__ __launch_bounds__(BLOCK) void dsnt_loss_kernel(
    const float* __restrict__ inp,
    const float* __restrict__ tgt,
    float* __restrict__ out)
{
    const int bc = blockIdx.x;
    const int t  = threadIdx.x;
    const float4* in4 = (const float4*)(inp + (size_t)bc * HW);
    const float4* tg4 = (const float4*)(tgt + (size_t)bc * HW);

    const float inv256 = 1.0f / 256.0f;

    // online-softmax state: running max m, denom l, weighted sums sx, sy
    float m = -FLT_MAX, l = 0.0f, sx = 0.0f, sy = 0.0f;
    // argmax state (first occurrence on ties -> '>' within a thread is enough
    // since each thread visits indices in increasing order)
    float bv = -FLT_MAX;
    int   bi = 0;

#pragma unroll
    for (int k = 0; k < F4_PER_THREAD; ++k) {
        const int f4 = t + k * BLOCK;      // float4 index within heatmap
        const float4 x = in4[f4];
        const float4 g = tg4[f4];
        const int e0 = f4 * 4;             // flat element index of x.x

        // ---- online softmax over 4 elements (same row: W=256 % 4 == 0) ----
        const float m4 = fmaxf(fmaxf(x.x, x.y), fmaxf(x.z, x.w));
        const float mn = fmaxf(m, m4);
        const float c  = __expf(m - mn);   // rescale old state (==1 if m unchanged)
        const float ex = __expf(x.x - mn);
        const float ey = __expf(x.y - mn);
        const float ez = __expf(x.z - mn);
        const float ew = __expf(x.w - mn);
        const float es = (ex + ey) + (ez + ew);

        const int   w0 = e0 & 255;         // x index of first element
        const int   hh = e0 >> 8;          // y index (shared by all 4)
        const float ysw = (float)(hh + 1) * inv256;
        // sum e_j * (w0 + 1 + j), scaled by 1/256 at the end
        const float sxl = ex * (float)(w0 + 1) + ey * (float)(w0 + 2)
                        + ez * (float)(w0 + 3) + ew * (float)(w0 + 4);

        l  = l  * c + es;
        sy = sy * c + ysw * es;
        sx = sx * c + sxl * inv256;
        m  = mn;

        // ---- argmax of target ----
        if (g.x > bv) { bv = g.x; bi = e0;     }
        if (g.y > bv) { bv = g.y; bi = e0 + 1; }
        if (g.z > bv) { bv = g.z; bi = e0 + 2; }
        if (g.w > bv) { bv = g.w; bi = e0 + 3; }
    }

    // ---- wave (64-lane) reduction ----
#pragma unroll
    for (int off = 32; off > 0; off >>= 1) {
        const float m2  = __shfl_down(m,  off);
        const float l2  = __shfl_down(l,  off);
        const float sx2 = __shfl_down(sx, off);
        const float sy2 = __shfl_down(sy, off);
        const float bv2 = __shfl_down(bv, off);
        const int   bi2 = __shfl_down(bi, off);

        const float mn = fmaxf(m, m2);
        const float c1 = __expf(m  - mn);
        const float c2 = __expf(m2 - mn);
        l  = l  * c1 + l2  * c2;
        sx = sx * c1 + sx2 * c2;
        sy = sy * c1 + sy2 * c2;
        m  = mn;
        if (bv2 > bv || (bv2 == bv && bi2 < bi)) { bv = bv2; bi = bi2; }
    }

    // ---- cross-wave reduction via LDS (16 waves) ----
    __shared__ float sm[16], sl[16], ssx[16], ssy[16], sbv[16];
    __shared__ int   sbi[16];
    const int wid  = t >> 6;
    const int lane = t & 63;
    if (lane == 0) {
        sm[wid] = m; sl[wid] = l; ssx[wid] = sx; ssy[wid] = sy;
        sbv[wid] = bv; sbi[wid] = bi;
    }
    __syncthreads();

    if (t == 0) {
        m = sm[0]; l = sl[0]; sx = ssx[0]; sy = ssy[0]; bv = sbv[0]; bi = sbi[0];
#pragma unroll
        for (int i = 1; i < 16; ++i) {
            const float mi = sm[i];
            const float mn = fmaxf(m, mi);
            const float c1 = __expf(m  - mn);
            const float c2 = __expf(mi - mn);
            l  = l  * c1 + sl[i]  * c2;
            sx = sx * c1 + ssx[i] * c2;
            sy = sy * c1 + ssy[i] * c2;
            m  = mn;
            if (sbv[i] > bv || (sbv[i] == bv && sbi[i] < bi)) { bv = sbv[i]; bi = sbi[i]; }
        }
        const float px = sx / l;
        const float py = sy / l;
        const float tx = (float)((bi & 255) + 1) * inv256;
        const float ty = (float)((bi >> 8) + 1) * inv256;
        const float dx = tx - px;
        const float dy = ty - py;
        const float ed = sqrtf(dx * dx + dy * dy);
        atomicAdd(out, ed * (1.0f / 32.0f));   // sum over (b,c) / B, B=32
    }
}

extern "C" void kernel_launch(void* const* d_in, const int* in_sizes, int n_in,
                              void* d_out, int out_size, void* d_ws, size_t ws_size,
                              hipStream_t stream) {
    const float* inp = (const float*)d_in[0];
    const float* tgt = (const float*)d_in[1];
    float* out = (float*)d_out;

    const int n_heatmaps = in_sizes[0] / HW;   // B*C = 256

    // d_out is poisoned to 0xAA before every launch -> zero it (async, capturable)
    hipMemsetAsync(out, 0, sizeof(float), stream);
    dsnt_loss_kernel<<<n_heatmaps, BLOCK, 0, stream>>>(inp, tgt, out);
}